// Round 2
// baseline (428.805 us; speedup 1.0000x reference)
//
#include <hip/hip_runtime.h>
#include <math.h>

#define TOKENS 16384
#define HID    4096
#define NEXP   64
#define TOPK   8
#define BT     64       // tokens per block (pass1)
#define BK     64       // k per LDS tile (pass1)
#define TAU    1e-3f    // min-gap threshold: >> fp32 dot error (~3e-6 sigma)
#define REFINE_BLOCKS 1024

// ---------------- pass 0: zero the flag counter (ws not re-poisoned) --------
__global__ void zero_cnt_kernel(int* cnt) {
    if (threadIdx.x == 0) cnt[0] = 0;
}

// ---------------- pass 1: fp32 GEMM + gap-checked top-8 ---------------------
// LDS: As/Bs transposed [kk][m], XOR-4 swizzle -> conflict-free ds_read_b128.
__global__ __launch_bounds__(256) void moe_gate_pass1(
    const float* __restrict__ hs,   // [TOKENS][HID]
    const float* __restrict__ w,    // [NEXP][HID]
    float* __restrict__ out_idx_f,  // [TOKENS][TOPK] indices as float
    float* __restrict__ out_gate,   // [TOKENS][TOPK]
    int* __restrict__ flag_cnt,     // ws[0]
    int* __restrict__ flag_list)    // ws[1..]
{
    __shared__ float smem[8192];          // 32 KiB: As(4096) + Bs(4096)
    float* As = smem;
    float* Bs = smem + 4096;

    const int tid = threadIdx.x;
    const int t0  = blockIdx.x * BT;
    const int tg  = tid & 15;             // token group (4 tokens)
    const int eg  = tid >> 4;             // expert group (4 experts)

    float acc[4][4];
    #pragma unroll
    for (int i = 0; i < 4; ++i)
        #pragma unroll
        for (int j = 0; j < 4; ++j)
            acc[i][j] = 0.0f;

    for (int k0 = 0; k0 < HID; k0 += BK) {
        __syncthreads();
        #pragma unroll
        for (int it = 0; it < 4; ++it) {
            int f4  = tid + it * 256;
            int row = f4 >> 4;
            int kk  = (f4 & 15) << 2;
            int c   = kk & 28;
            int col = row ^ c;
            float4 a = *(const float4*)(hs + (size_t)(t0 + row) * HID + k0 + kk);
            As[(kk + 0) * 64 + col] = a.x;
            As[(kk + 1) * 64 + col] = a.y;
            As[(kk + 2) * 64 + col] = a.z;
            As[(kk + 3) * 64 + col] = a.w;
            float4 b = *(const float4*)(w + (size_t)row * HID + k0 + kk);
            Bs[(kk + 0) * 64 + col] = b.x;
            Bs[(kk + 1) * 64 + col] = b.y;
            Bs[(kk + 2) * 64 + col] = b.z;
            Bs[(kk + 3) * 64 + col] = b.w;
        }
        __syncthreads();
        #pragma unroll
        for (int kk = 0; kk < BK; ++kk) {
            int c = kk & 28;
            float4 av = *(const float4*)(As + kk * 64 + ((tg << 2) ^ c));
            float4 bv = *(const float4*)(Bs + kk * 64 + ((eg << 2) ^ c));
            acc[0][0] = fmaf(av.x, bv.x, acc[0][0]);
            acc[0][1] = fmaf(av.x, bv.y, acc[0][1]);
            acc[0][2] = fmaf(av.x, bv.z, acc[0][2]);
            acc[0][3] = fmaf(av.x, bv.w, acc[0][3]);
            acc[1][0] = fmaf(av.y, bv.x, acc[1][0]);
            acc[1][1] = fmaf(av.y, bv.y, acc[1][1]);
            acc[1][2] = fmaf(av.y, bv.z, acc[1][2]);
            acc[1][3] = fmaf(av.y, bv.w, acc[1][3]);
            acc[2][0] = fmaf(av.z, bv.x, acc[2][0]);
            acc[2][1] = fmaf(av.z, bv.y, acc[2][1]);
            acc[2][2] = fmaf(av.z, bv.z, acc[2][2]);
            acc[2][3] = fmaf(av.z, bv.w, acc[2][3]);
            acc[3][0] = fmaf(av.w, bv.x, acc[3][0]);
            acc[3][1] = fmaf(av.w, bv.y, acc[3][1]);
            acc[3][2] = fmaf(av.w, bv.z, acc[3][2]);
            acc[3][3] = fmaf(av.w, bv.w, acc[3][3]);
        }
    }

    __syncthreads();
    float* lg = smem;   // [BT][65] padded
    #pragma unroll
    for (int i = 0; i < 4; ++i)
        #pragma unroll
        for (int j = 0; j < 4; ++j)
            lg[(tg * 4 + i) * 65 + (eg * 4 + j)] = acc[i][j];
    __syncthreads();

    if (tid < BT) {
        const int t = tid;
        float v[9];
        int   id[9];
        #pragma unroll
        for (int j = 0; j < 9; ++j) { v[j] = -INFINITY; id[j] = -1; }
        for (int e = 0; e < NEXP; ++e) {
            float x = lg[t * 65 + e];
            if (x > v[8]) {
                int p = 8;
                while (p > 0 && v[p - 1] < x) {
                    v[p]  = v[p - 1];
                    id[p] = id[p - 1];
                    --p;
                }
                v[p]  = x;
                id[p] = e;
            }
        }
        // min adjacent gap across top-9 (ordering + membership certificate)
        float g = v[0] - v[1];
        #pragma unroll
        for (int j = 1; j < 8; ++j) g = fminf(g, v[j] - v[j + 1]);

        if (g < TAU) {
            int slot = atomicAdd(flag_cnt, 1);
            flag_list[slot] = t0 + t;
        } else {
            float m = v[0];
            float ex[TOPK];
            float s = 0.0f;
            #pragma unroll
            for (int j = 0; j < TOPK; ++j) { ex[j] = expf(v[j] - m); s += ex[j]; }
            float inv = 1.0f / s;
            size_t base = (size_t)(t0 + t) * TOPK;
            #pragma unroll
            for (int j = 0; j < TOPK; ++j) {
                out_idx_f[base + j] = (float)id[j];
                out_gate[base + j]  = ex[j] * inv;
            }
        }
    }
}

// ---------------- pass 2: fp64 exact recompute for flagged tokens -----------
// One token per block-iteration; 256 threads = 64 experts x 4 k-quarters.
// fp32*fp32 products are exact in fp64; fixed reduction order -> deterministic.
__global__ __launch_bounds__(256) void moe_gate_refine(
    const float* __restrict__ hs,
    const float* __restrict__ w,
    float* __restrict__ out_idx_f,
    float* __restrict__ out_gate,
    const int* __restrict__ flag_cnt,
    const int* __restrict__ flag_list)
{
    __shared__ double part[4][64];
    __shared__ double lgd[64];
    const int tid = threadIdx.x;
    const int e   = tid & 63;
    const int q   = tid >> 6;
    const int n   = flag_cnt[0];

    for (int fi = blockIdx.x; fi < n; fi += gridDim.x) {
        const int t = flag_list[fi];
        const float4* hp = (const float4*)(hs + (size_t)t * HID + q * 1024);
        const float4* wp = (const float4*)(w  + (size_t)e * HID + q * 1024);
        double p0 = 0.0, p1 = 0.0, p2 = 0.0, p3 = 0.0;
        #pragma unroll 4
        for (int k = 0; k < 256; ++k) {
            float4 a = hp[k];
            float4 b = wp[k];
            p0 = fma((double)a.x, (double)b.x, p0);
            p1 = fma((double)a.y, (double)b.y, p1);
            p2 = fma((double)a.z, (double)b.z, p2);
            p3 = fma((double)a.w, (double)b.w, p3);
        }
        part[q][e] = (p0 + p1) + (p2 + p3);
        __syncthreads();
        if (q == 0)
            lgd[e] = (part[0][e] + part[1][e]) + (part[2][e] + part[3][e]);
        __syncthreads();
        if (tid == 0) {
            double v[TOPK];
            int    id[TOPK];
            #pragma unroll
            for (int j = 0; j < TOPK; ++j) { v[j] = -INFINITY; id[j] = -1; }
            for (int ee = 0; ee < NEXP; ++ee) {
                double x = lgd[ee];
                if (x > v[TOPK - 1]) {
                    int p = TOPK - 1;
                    while (p > 0 && v[p - 1] < x) {
                        v[p]  = v[p - 1];
                        id[p] = id[p - 1];
                        --p;
                    }
                    v[p]  = x;
                    id[p] = ee;
                }
            }
            double m = v[0];
            double ex[TOPK];
            double s = 0.0;
            #pragma unroll
            for (int j = 0; j < TOPK; ++j) { ex[j] = exp(v[j] - m); s += ex[j]; }
            double inv = 1.0 / s;
            size_t base = (size_t)t * TOPK;
            #pragma unroll
            for (int j = 0; j < TOPK; ++j) {
                out_idx_f[base + j] = (float)id[j];
                out_gate[base + j]  = (float)(ex[j] * inv);
            }
        }
        __syncthreads();
    }
}

extern "C" void kernel_launch(void* const* d_in, const int* in_sizes, int n_in,
                              void* d_out, int out_size, void* d_ws, size_t ws_size,
                              hipStream_t stream) {
    const float* hs = (const float*)d_in[0];   // [16384][4096] f32
    const float* w  = (const float*)d_in[1];   // [64][4096] f32
    float* out      = (float*)d_out;
    float* out_idx  = out;
    float* out_gate = out + (size_t)TOKENS * TOPK;

    int* flag_cnt  = (int*)d_ws;
    int* flag_list = flag_cnt + 1;

    hipLaunchKernelGGL(zero_cnt_kernel, dim3(1), dim3(64), 0, stream, flag_cnt);
    hipLaunchKernelGGL(moe_gate_pass1, dim3(TOKENS / BT), dim3(256), 0, stream,
                       hs, w, out_idx, out_gate, flag_cnt, flag_list);
    hipLaunchKernelGGL(moe_gate_refine, dim3(REFINE_BLOCKS), dim3(256), 0, stream,
                       hs, w, out_idx, out_gate, flag_cnt, flag_list);
}

// Round 3
// 175.348 us; speedup vs baseline: 2.4454x; 2.4454x over previous
//
#include <hip/hip_runtime.h>
#include <math.h>

#define TOKENS 16384
#define HID    4096
#define NEXP   64
#define TOPK   8
#define BT     64               // tokens per block (pass1)
#define BK     64               // k per LDS tile
#define NTILES (HID / BK)       // 64
#define TAU    5e-4f            // >> 3-split logit error (~5e-5 max)
#define REFINE_BLOCKS 1024

typedef short          bf16x8 __attribute__((ext_vector_type(8)));
typedef unsigned short u16x8  __attribute__((ext_vector_type(8)));
typedef float          f32x4  __attribute__((ext_vector_type(4)));

// LDS: 2 buffers x 32KB; within a buffer: Ahi(8K) Alo(8K) Bhi(8K) Blo(8K)
// Tiles are [row][k] bf16, 64 rows x 64 k = 128B/row, XOR-swizzled:
//   byte ^= (row&7)<<4   (applied identically on write and read)
#define BUF_STRIDE 32768
#define AHI 0
#define ALO 8192
#define BHI 16384
#define BLO 24576

__device__ __forceinline__ unsigned short bf16_rtn(float x) {
    unsigned u = __builtin_bit_cast(unsigned, x);
    u += 0x7FFFu + ((u >> 16) & 1u);
    return (unsigned short)(u >> 16);
}

__device__ __forceinline__ void splitf(float x, unsigned short& h, unsigned short& l) {
    h = bf16_rtn(x);
    float hf = __builtin_bit_cast(float, (unsigned)h << 16);
    l = bf16_rtn(x - hf);       // x - hf exact (Sterbenz); residual <= 2^-18 |x|
}

__global__ void zero_cnt_kernel(int* cnt) {
    if (threadIdx.x == 0) cnt[0] = 0;
}

// ---------------- pass 1: bf16 3-split MFMA GEMM + gap-checked top-8 --------
__global__ __launch_bounds__(256) void moe_gate_pass1(
    const float* __restrict__ hs,   // [TOKENS][HID]
    const float* __restrict__ w,    // [NEXP][HID]  (B^T: K-contiguous)
    float* __restrict__ out_idx_f,
    float* __restrict__ out_gate,
    int* __restrict__ flag_cnt,
    int* __restrict__ flag_list,
    int flag_cap)
{
    __shared__ char lds[65536];
    const int tid = threadIdx.x;
    const int t0  = blockIdx.x * BT;

    // staging assignment: thread -> (row, 16-float k chunk)
    const int arow = tid >> 2;              // 0..63 (token row / expert row)
    const int kq   = (tid & 3) << 4;        // float offset 0,16,32,48
    const size_t abase = (size_t)(t0 + arow) * HID + kq;
    const size_t bbase = (size_t)arow * HID + kq;

    // wave/fragment assignment
    const int lane = tid & 63;
    const int wv   = tid >> 6;              // 4 waves
    const int wm   = wv & 1;                // token half (32)
    const int wn   = wv >> 1;               // expert half (32)
    const int sw   = (lane & 7) << 4;       // read-side swizzle ((row&7)<<4, row%8==lane%8)
    const int kgb  = (lane >> 4) << 4;      // k-group byte offset 0,16,32,48
    const int aoff0 = (wm * 32 + (lane & 15)) * 128 + kgb;
    const int boff0 = (wn * 32 + (lane & 15)) * 128 + kgb;

    float areg[16], breg[16];
    u16x8 vah[2], val_[2], vbh[2], vbl[2];

    f32x4 acc[2][2];
    #pragma unroll
    for (int i = 0; i < 2; ++i)
        #pragma unroll
        for (int j = 0; j < 2; ++j) {
            acc[i][j][0] = 0.f; acc[i][j][1] = 0.f;
            acc[i][j][2] = 0.f; acc[i][j][3] = 0.f;
        }

    auto LOADS = [&](int t) {
        const f32x4* pa = (const f32x4*)(hs + abase + (size_t)t * BK);
        const f32x4* pb = (const f32x4*)(w  + bbase + (size_t)t * BK);
        #pragma unroll
        for (int i = 0; i < 4; ++i) {
            ((f32x4*)areg)[i] = pa[i];
            ((f32x4*)breg)[i] = pb[i];
        }
    };

    auto CONV = [&]() {
        #pragma unroll
        for (int c = 0; c < 2; ++c)
            #pragma unroll
            for (int i = 0; i < 8; ++i) {
                unsigned short h, l;
                splitf(areg[c * 8 + i], h, l); vah[c][i] = h; val_[c][i] = l;
                splitf(breg[c * 8 + i], h, l); vbh[c][i] = h; vbl[c][i] = l;
            }
    };

    auto WRITE = [&](int buf) {
        char* bp = lds + buf * BUF_STRIDE;
        const int base = arow * 128 + (kq << 1);
        const int swz  = (arow & 7) << 4;
        *(u16x8*)(bp + AHI + ((base +  0) ^ swz)) = vah[0];
        *(u16x8*)(bp + AHI + ((base + 16) ^ swz)) = vah[1];
        *(u16x8*)(bp + ALO + ((base +  0) ^ swz)) = val_[0];
        *(u16x8*)(bp + ALO + ((base + 16) ^ swz)) = val_[1];
        *(u16x8*)(bp + BHI + ((base +  0) ^ swz)) = vbh[0];
        *(u16x8*)(bp + BHI + ((base + 16) ^ swz)) = vbh[1];
        *(u16x8*)(bp + BLO + ((base +  0) ^ swz)) = vbl[0];
        *(u16x8*)(bp + BLO + ((base + 16) ^ swz)) = vbl[1];
    };

    auto COMPUTE = [&](int buf) {
        const char* bp = lds + buf * BUF_STRIDE;
        #pragma unroll
        for (int kk = 0; kk < 2; ++kk) {        // two K=32 steps per tile
            bf16x8 fah[2], fal[2], fbh[2], fbl[2];
            #pragma unroll
            for (int mi = 0; mi < 2; ++mi) {
                int ao = (aoff0 + mi * 16 * 128 + kk * 64) ^ sw;
                fah[mi] = *(const bf16x8*)(bp + AHI + ao);
                fal[mi] = *(const bf16x8*)(bp + ALO + ao);
            }
            #pragma unroll
            for (int ni = 0; ni < 2; ++ni) {
                int bo = (boff0 + ni * 16 * 128 + kk * 64) ^ sw;
                fbh[ni] = *(const bf16x8*)(bp + BHI + bo);
                fbl[ni] = *(const bf16x8*)(bp + BLO + bo);
            }
            #pragma unroll
            for (int mi = 0; mi < 2; ++mi)
                #pragma unroll
                for (int ni = 0; ni < 2; ++ni) {
                    acc[mi][ni] = __builtin_amdgcn_mfma_f32_16x16x32_bf16(
                        fah[mi], fbh[ni], acc[mi][ni], 0, 0, 0);
                    acc[mi][ni] = __builtin_amdgcn_mfma_f32_16x16x32_bf16(
                        fah[mi], fbl[ni], acc[mi][ni], 0, 0, 0);
                    acc[mi][ni] = __builtin_amdgcn_mfma_f32_16x16x32_bf16(
                        fal[mi], fbh[ni], acc[mi][ni], 0, 0, 0);
                }
        }
    };

    // ---- pipelined K loop (double-buffered LDS) ----
    LOADS(0);
    CONV();
    WRITE(0);
    __syncthreads();
    LOADS(1);
    int cur = 0;
    for (int t = 0; t < NTILES - 1; ++t) {
        COMPUTE(cur);
        CONV();                                 // waits loads(t+1) via reg deps
        if (t < NTILES - 2) LOADS(t + 2);       // reissue early: stay in flight
        __syncthreads();                        // all waves done reading buf[cur]
        WRITE(cur ^ 1);
        __syncthreads();                        // writes visible for next iter
        cur ^= 1;
    }
    COMPUTE(cur);
    __syncthreads();

    // ---- epilogue: acc -> LDS logits [64][65] ----
    float* lg = (float*)lds;
    #pragma unroll
    for (int mi = 0; mi < 2; ++mi)
        #pragma unroll
        for (int ni = 0; ni < 2; ++ni)
            #pragma unroll
            for (int r = 0; r < 4; ++r) {
                int trow = wm * 32 + mi * 16 + ((lane >> 4) << 2) + r;
                int col  = wn * 32 + ni * 16 + (lane & 15);
                lg[trow * 65 + col] = acc[mi][ni][r];
            }
    __syncthreads();

    // ---- per-token top-9 + gap certificate + softmax ----
    if (tid < BT) {
        const int t = tid;
        float v[9];
        int   id[9];
        #pragma unroll
        for (int j = 0; j < 9; ++j) { v[j] = -INFINITY; id[j] = -1; }
        for (int e = 0; e < NEXP; ++e) {
            float x = lg[t * 65 + e];
            if (x > v[8]) {
                int p = 8;
                while (p > 0 && v[p - 1] < x) {
                    v[p]  = v[p - 1];
                    id[p] = id[p - 1];
                    --p;
                }
                v[p]  = x;
                id[p] = e;
            }
        }
        float g = v[0] - v[1];
        #pragma unroll
        for (int j = 1; j < 8; ++j) g = fminf(g, v[j] - v[j + 1]);

        bool deferred = false;
        if (g < TAU) {
            int slot = atomicAdd(flag_cnt, 1);
            if (slot < flag_cap) {
                flag_list[slot] = t0 + t;
                deferred = true;
            }
        }
        if (!deferred) {
            float m = v[0];
            float ex[TOPK];
            float s = 0.0f;
            #pragma unroll
            for (int j = 0; j < TOPK; ++j) { ex[j] = expf(v[j] - m); s += ex[j]; }
            float inv = 1.0f / s;
            size_t base = (size_t)(t0 + t) * TOPK;
            #pragma unroll
            for (int j = 0; j < TOPK; ++j) {
                out_idx_f[base + j] = (float)id[j];
                out_gate[base + j]  = ex[j] * inv;
            }
        }
    }
}

// ---------------- pass 2: fp64 exact recompute, coalesced -------------------
__global__ __launch_bounds__(256) void moe_gate_refine(
    const float* __restrict__ hs,
    const float* __restrict__ w,
    float* __restrict__ out_idx_f,
    float* __restrict__ out_gate,
    const int* __restrict__ flag_cnt,
    const int* __restrict__ flag_list,
    int flag_cap)
{
    __shared__ float  hrow[HID];
    __shared__ double lgw[4][NEXP];
    __shared__ double lgd[NEXP];
    const int tid  = threadIdx.x;
    const int lane = tid & 63;
    const int wv   = tid >> 6;

    int n = flag_cnt[0];
    if (n > flag_cap) n = flag_cap;

    for (int fi = blockIdx.x; fi < n; fi += gridDim.x) {
        const int t = flag_list[fi];
        #pragma unroll
        for (int i = 0; i < 4; ++i)
            ((f32x4*)hrow)[tid + 256 * i] =
                ((const f32x4*)(hs + (size_t)t * HID))[tid + 256 * i];
        __syncthreads();

        for (int e = 0; e < NEXP; ++e) {
            const f32x4* wp = (const f32x4*)(w + (size_t)e * HID);
            double s0 = 0.0, s1 = 0.0, s2 = 0.0, s3 = 0.0;
            #pragma unroll
            for (int i = 0; i < 4; ++i) {
                f32x4 wf = wp[tid + 256 * i];                // coalesced
                f32x4 af = ((const f32x4*)hrow)[tid + 256 * i];
                s0 = fma((double)wf[0], (double)af[0], s0);
                s1 = fma((double)wf[1], (double)af[1], s1);
                s2 = fma((double)wf[2], (double)af[2], s2);
                s3 = fma((double)wf[3], (double)af[3], s3);
            }
            double d = (s0 + s1) + (s2 + s3);
            #pragma unroll
            for (int off = 32; off > 0; off >>= 1)
                d += __shfl_down(d, off, 64);                // fixed tree order
            if (lane == 0) lgw[wv][e] = d;
        }
        __syncthreads();
        if (tid < NEXP)
            lgd[tid] = (lgw[0][tid] + lgw[1][tid]) + (lgw[2][tid] + lgw[3][tid]);
        __syncthreads();

        if (tid == 0) {
            double v[TOPK];
            int    id[TOPK];
            #pragma unroll
            for (int j = 0; j < TOPK; ++j) { v[j] = -INFINITY; id[j] = -1; }
            for (int e = 0; e < NEXP; ++e) {
                double x = lgd[e];
                if (x > v[TOPK - 1]) {
                    int p = TOPK - 1;
                    while (p > 0 && v[p - 1] < x) {
                        v[p]  = v[p - 1];
                        id[p] = id[p - 1];
                        --p;
                    }
                    v[p]  = x;
                    id[p] = e;
                }
            }
            double m = v[0];
            double ex[TOPK];
            double s = 0.0;
            #pragma unroll
            for (int j = 0; j < TOPK; ++j) { ex[j] = exp(v[j] - m); s += ex[j]; }
            double inv = 1.0 / s;
            size_t base = (size_t)t * TOPK;
            #pragma unroll
            for (int j = 0; j < TOPK; ++j) {
                out_idx_f[base + j] = (float)id[j];
                out_gate[base + j]  = (float)(ex[j] * inv);
            }
        }
        __syncthreads();   // before next iteration overwrites hrow/lgw
    }
}

extern "C" void kernel_launch(void* const* d_in, const int* in_sizes, int n_in,
                              void* d_out, int out_size, void* d_ws, size_t ws_size,
                              hipStream_t stream) {
    const float* hs = (const float*)d_in[0];
    const float* w  = (const float*)d_in[1];
    float* out      = (float*)d_out;
    float* out_idx  = out;
    float* out_gate = out + (size_t)TOKENS * TOPK;

    int* flag_cnt  = (int*)d_ws;
    int* flag_list = flag_cnt + 1;
    int flag_cap   = (int)(ws_size / sizeof(int)) - 1;
    if (flag_cap > TOKENS) flag_cap = TOKENS;
    if (flag_cap < 0) flag_cap = 0;

    hipLaunchKernelGGL(zero_cnt_kernel, dim3(1), dim3(64), 0, stream, flag_cnt);
    hipLaunchKernelGGL(moe_gate_pass1, dim3(TOKENS / BT), dim3(256), 0, stream,
                       hs, w, out_idx, out_gate, flag_cnt, flag_list, flag_cap);
    hipLaunchKernelGGL(moe_gate_refine, dim3(REFINE_BLOCKS), dim3(256), 0, stream,
                       hs, w, out_idx, out_gate, flag_cnt, flag_list, flag_cap);
}